// Round 5
// baseline (1155.568 us; speedup 1.0000x reference)
//
#include <hip/hip_runtime.h>
#include <stdint.h>

// GLA block for MI355X (gfx950).
// B=8 S=2048 D=1024 H=4 DK=128 DV=256 CHUNK=64 (32 chunks), MLP_H=4096.
// R5: gemm256 restructured to big-cluster schedule: per K-tile = 2x 32-MFMA
// clusters, 2 barriers (WAR + confirm), 1 counted vmcnt(8) (0 only at tail),
// front-loaded frag reads so ds_read drains under MFMA issue.

typedef unsigned short u16t;
typedef __attribute__((ext_vector_type(8))) short bf16x8;
typedef __attribute__((ext_vector_type(4))) float f32x4;
typedef __attribute__((ext_vector_type(4))) unsigned short u16x4;

__device__ __forceinline__ float bf2f(unsigned short u){ union{unsigned int i; float f;} v; v.i=((unsigned int)u)<<16; return v.f; }
__device__ __forceinline__ unsigned short f2bf(float f){ union{unsigned int i; float f;} v; v.f=f; unsigned int r=v.i+0x7FFFu+((v.i>>16)&1u); return (unsigned short)(r>>16); }
__device__ __forceinline__ f32x4 cvt4(u16x4 u){ f32x4 r; r[0]=bf2f(u[0]); r[1]=bf2f(u[1]); r[2]=bf2f(u[2]); r[3]=bf2f(u[3]); return r; }
__device__ __forceinline__ u16x4 pack4(f32x4 f){ u16x4 r; r[0]=f2bf(f[0]); r[1]=f2bf(f[1]); r[2]=f2bf(f[2]); r[3]=f2bf(f[3]); return r; }

__device__ __forceinline__ void gload_lds16(const unsigned short* g, unsigned short* l)
{
  __builtin_amdgcn_global_load_lds(
      (const __attribute__((address_space(1))) unsigned int*)g,
      (__attribute__((address_space(3))) unsigned int*)l,
      16, 0, 0);
}

// ---------------- transpose f32 [Kin][N] -> bf16 [N][Kin] ----------------
__global__ void k_transpose(const float* __restrict__ src, unsigned short* __restrict__ dst, int Kin, int N)
{
  __shared__ float tile[32][33];
  const int n0 = blockIdx.x*32, k0 = blockIdx.y*32;
  const int tx = threadIdx.x, ty = threadIdx.y;
  #pragma unroll
  for (int i = 0; i < 4; ++i) {
    tile[ty + i*8][tx] = src[(size_t)(k0 + ty + i*8)*N + n0 + tx];
  }
  __syncthreads();
  #pragma unroll
  for (int i = 0; i < 4; ++i) {
    dst[(size_t)(n0 + ty + i*8)*Kin + k0 + tx] = f2bf(tile[tx][ty + i*8]);
  }
}

// ---------------- Wgk = Wgk1[1024,16] @ Wgk2[16,512] -> bf16 transposed rows [512][1024] ----------------
__global__ void k_wgk(const float* __restrict__ Wgk1, const float* __restrict__ Wgk2, unsigned short* __restrict__ dstT)
{
  const int idx = blockIdx.x*256 + threadIdx.x;   // 1024*512 total
  const int i = idx & 1023, j = idx >> 10;
  float s = 0.f;
  #pragma unroll
  for (int r = 0; r < 16; ++r) s += Wgk1[i*16 + r] * Wgk2[r*512 + j];
  dstT[(size_t)j*1024 + i] = f2bf(s);
}

// ---------------- LayerNorm row=1024, f32 in -> bf16 out ----------------
__global__ __launch_bounds__(256) void k_layernorm(const float* __restrict__ x, const float* __restrict__ g,
                                                   const float* __restrict__ b, unsigned short* __restrict__ out)
{
  const int row = blockIdx.x, tid = threadIdx.x;
  const float4 xv = *(const float4*)&x[(size_t)row*1024 + tid*4];
  float s  = xv.x + xv.y + xv.z + xv.w;
  float sq = xv.x*xv.x + xv.y*xv.y + xv.z*xv.z + xv.w*xv.w;
  #pragma unroll
  for (int o = 32; o > 0; o >>= 1) { s += __shfl_xor(s, o); sq += __shfl_xor(sq, o); }
  __shared__ float red[8];
  const int w = tid >> 6;
  if ((tid & 63) == 0) { red[w] = s; red[4 + w] = sq; }
  __syncthreads();
  s  = red[0] + red[1] + red[2] + red[3];
  sq = red[4] + red[5] + red[6] + red[7];
  const float mu = s * (1.f/1024.f);
  const float var = sq * (1.f/1024.f) - mu*mu;
  const float rs = rsqrtf(var + 1e-5f);
  float xe[4] = {xv.x, xv.y, xv.z, xv.w};
  u16x4 o4;
  #pragma unroll
  for (int i = 0; i < 4; ++i) {
    const int c = tid*4 + i;
    o4[i] = f2bf((xe[i] - mu) * rs * g[c] + b[c]);
  }
  *(u16x4*)&out[(size_t)row*1024 + tid*4] = o4;
}

// ---------------- 256x256 big-cluster bf16 MFMA GEMM: C = A[M,K] @ Bt[N,K]^T ----------------
// 512 threads = 8 waves (2M x 4N); per-wave 128x64 output.
// LDS: 2 bufs x 4 chunks {Ah0,Ah1,Bh0,Bh1} x 16KB = 128 KiB. XOR-swizzled (T2).
// Per K-tile: lgkm; 32 MFMA; read Ah1; lgkm; 32 MFMA; barrier(WAR); stage j+2;
// vmcnt(8|0); barrier(confirm); read next-tile Ah0/Bh0/Bh1.
// EPI: 0 = store bf16; 1 = +resid -> f32; 2 = +bias, gelu -> bf16; 3 = +bias +resid -> f32
template<int EPI>
__global__ __launch_bounds__(512, 2)
void gemm256(const unsigned short* __restrict__ A, const unsigned short* __restrict__ Bt,
             int N, int K,
             float* outF, unsigned short* outH,
             const float* resid, const float* bias)
{
  __shared__ __align__(16) unsigned short lds[65536];   // 128 KiB
  const int tid = threadIdx.x;
  const int lane = tid & 63, w = tid >> 6;
  const int wr = w >> 2, wc = w & 3;
  const int l15 = lane & 15, lq = lane >> 4;

  // bijective XCD-aware swizzle (m204)
  const int nwg = gridDim.x * gridDim.y;
  const int bid = blockIdx.y * gridDim.x + blockIdx.x;
  const int q = nwg >> 3, r = nwg & 7;
  const int xcd = bid & 7, lid = bid >> 3;
  const int sw = (xcd < r ? xcd*(q+1) : r*(q+1) + (xcd - r)*q) + lid;
  const int row0 = (sw / gridDim.x) * 256;
  const int col0 = (sw % gridDim.x) * 256;

  // staging: per chunk 2 loads; load L covers rows L*64..L*64+63 of the 128-row half
  const int rA_ = tid >> 3;                              // row within 64-row group
  const int cswz = 8 * ((tid & 7) ^ (rA_ & 7));          // pre-swizzled source col (elems)
  const unsigned short* baseA[2][2];
  const unsigned short* baseB[2][2];
  #pragma unroll
  for (int h = 0; h < 2; ++h)
    #pragma unroll
    for (int L = 0; L < 2; ++L) {
      baseA[h][L] = A  + (size_t)(row0 + h*128 + L*64 + rA_) * K + cswz;
      baseB[h][L] = Bt + (size_t)(col0 + h*128 + L*64 + rA_) * K + cswz;
    }

  const int NT = K >> 6;          // 64-wide K tiles (NT >= 2, K%128==0)

  f32x4 acc[8][4];
  #pragma unroll
  for (int m = 0; m < 8; ++m)
    #pragma unroll
    for (int n = 0; n < 4; ++n) { acc[m][n][0]=0.f; acc[m][n][1]=0.f; acc[m][n][2]=0.f; acc[m][n][3]=0.f; }

  bf16x8 af[4][2];          // A frags (mm, khalf) — alternates Ah0/Ah1/Ah0(next)...
  bf16x8 bfr[2][2][2];      // B frags (qn, nn, khalf)

  // chunk ids in LDS: 0=Ah0, 1=Ah1, 2=Bh0, 3=Bh1 at buf*32768 + CH*8192
  #define STAGE4(T)                                                            \
    {                                                                          \
      const int dbase = ((T) & 1) * 32768;                                     \
      const int ktt = (T) << 6;                                                \
      _Pragma("unroll")                                                        \
      for (int L = 0; L < 2; ++L) {                                            \
        gload_lds16(baseA[0][L] + ktt, (unsigned short*)&lds[dbase +         L*4096 + w*512]); \
        gload_lds16(baseA[1][L] + ktt, (unsigned short*)&lds[dbase +  8192 + L*4096 + w*512]); \
        gload_lds16(baseB[0][L] + ktt, (unsigned short*)&lds[dbase + 16384 + L*4096 + w*512]); \
        gload_lds16(baseB[1][L] + ktt, (unsigned short*)&lds[dbase + 24576 + L*4096 + w*512]); \
      }                                                                        \
    }

  #define DS_A(CB)                                                             \
    { _Pragma("unroll")                                                        \
      for (int mm = 0; mm < 4; ++mm) {                                         \
        const int rl = wr*64 + mm*16 + l15;                                    \
        const int co = (l15 & 7) * 8;                                          \
        af[mm][0] = *(const bf16x8*)&lds[(CB) + rl*64 + ((lq*8) ^ co)];        \
        af[mm][1] = *(const bf16x8*)&lds[(CB) + rl*64 + ((32 + lq*8) ^ co)];   \
      } }

  #define DS_B(CB, QN)                                                         \
    { _Pragma("unroll")                                                        \
      for (int nn = 0; nn < 2; ++nn) {                                         \
        const int rl = wc*32 + nn*16 + l15;                                    \
        const int co = (l15 & 7) * 8;                                          \
        bfr[QN][nn][0] = *(const bf16x8*)&lds[(CB) + (2+(QN))*8192 + rl*64 + ((lq*8) ^ co)];      \
        bfr[QN][nn][1] = *(const bf16x8*)&lds[(CB) + (2+(QN))*8192 + rl*64 + ((32 + lq*8) ^ co)]; \
      } }

  #define MMA2(QM)                                                             \
    { __builtin_amdgcn_s_setprio(1);                                           \
      _Pragma("unroll")                                                        \
      for (int mm = 0; mm < 4; ++mm)                                           \
        _Pragma("unroll")                                                      \
        for (int qn = 0; qn < 2; ++qn)                                         \
          _Pragma("unroll")                                                    \
          for (int nn = 0; nn < 2; ++nn) {                                     \
            acc[(QM)*4+mm][qn*2+nn] = __builtin_amdgcn_mfma_f32_16x16x32_bf16( \
                af[mm][0], bfr[qn][nn][0], acc[(QM)*4+mm][qn*2+nn], 0, 0, 0);  \
            acc[(QM)*4+mm][qn*2+nn] = __builtin_amdgcn_mfma_f32_16x16x32_bf16( \
                af[mm][1], bfr[qn][nn][1], acc[(QM)*4+mm][qn*2+nn], 0, 0, 0);  \
          }                                                                    \
      __builtin_amdgcn_s_setprio(0); }

  // prologue: stage tiles 0,1; confirm tile 0; front-load its frags
  STAGE4(0); STAGE4(1);
  asm volatile("s_waitcnt vmcnt(8)" ::: "memory");
  __builtin_amdgcn_sched_barrier(0);
  __builtin_amdgcn_s_barrier();
  __builtin_amdgcn_sched_barrier(0);
  DS_A(0); DS_B(0, 0); DS_B(0, 1);

  for (int j = 0; j < NT; ++j) {
    const int B0 = (j & 1) * 32768;
    const int B1 = B0 ^ 32768;

    asm volatile("s_waitcnt lgkmcnt(0)" ::: "memory");
    __builtin_amdgcn_sched_barrier(0);
    MMA2(0);
    DS_A(B0 + 8192);                         // Ah1(j) — ages under MFMA issue
    asm volatile("s_waitcnt lgkmcnt(0)" ::: "memory");
    __builtin_amdgcn_sched_barrier(0);
    MMA2(1);

    __builtin_amdgcn_s_barrier();            // (A) WAR: all waves done reading buf B0
    __builtin_amdgcn_sched_barrier(0);
    if (j + 2 < NT) STAGE4(j + 2);           // overwrite buf B0 with tile j+2
    if (j + 1 < NT) {
      if (j + 2 < NT) { asm volatile("s_waitcnt vmcnt(8)" ::: "memory"); }
      else            { asm volatile("s_waitcnt vmcnt(0)" ::: "memory"); }
      __builtin_amdgcn_sched_barrier(0);
      __builtin_amdgcn_s_barrier();          // (B) confirm tile j+1 fully landed
      __builtin_amdgcn_sched_barrier(0);
      DS_A(B1); DS_B(B1, 0); DS_B(B1, 1);    // front-load next tile's frags
    }
  }
  #undef STAGE4
  #undef DS_A
  #undef DS_B
  #undef MMA2

  // epilogue
  #pragma unroll
  for (int qm = 0; qm < 2; ++qm)
    #pragma unroll
    for (int mm = 0; mm < 4; ++mm)
      #pragma unroll
      for (int qn = 0; qn < 2; ++qn)
        #pragma unroll
        for (int nn = 0; nn < 2; ++nn)
          #pragma unroll
          for (int ii = 0; ii < 4; ++ii) {
            const int rr = row0 + qm*128 + wr*64 + mm*16 + lq*4 + ii;
            const int cc = col0 + qn*128 + wc*32 + nn*16 + l15;
            const size_t idx = (size_t)rr * N + cc;
            const float v = acc[qm*4+mm][qn*2+nn][ii];
            if constexpr (EPI == 0) {
              outH[idx] = f2bf(v);
            } else if constexpr (EPI == 1) {
              outF[idx] = v + resid[idx];
            } else if constexpr (EPI == 2) {
              const float tt = v + bias[cc];
              outH[idx] = f2bf(0.5f * tt * (1.f + erff(tt * 0.70710678118654752f)));
            } else {
              outF[idx] = v + bias[cc] + resid[idx];
            }
          }
}

// ---------------- scan prep: per (bh, chunk): cumsum gates, write qt/kt bf16, eac f32 ----------------
__global__ __launch_bounds__(128) void k_scanprep(const unsigned short* __restrict__ proj, const float* __restrict__ bgk,
                                                  unsigned short* __restrict__ qt, unsigned short* __restrict__ kt,
                                                  float* __restrict__ eac)
{
  const int c = blockIdx.x & 31, bh = blockIdx.x >> 5;
  const int b = bh >> 2, h = bh & 3;
  const int dk = threadIdx.x;
  const size_t tok0 = (size_t)b*2048 + c*64;
  const float bg = bgk[h*128 + dk];
  float A = 0.f, ea = 1.f;
  for (int t = 0; t < 64; ++t) {
    const size_t prow = (tok0 + t) * 3584;
    const float qv = bf2f(proj[prow + h*128 + dk]);
    const float kv = bf2f(proj[prow + 512 + h*128 + dk]);
    const float z = bf2f(proj[prow + 3072 + h*128 + dk]) + bg;
    const float ls = (z >= 0.f) ? -log1pf(expf(-z)) : (z - log1pf(expf(z)));
    A += ls * 0.0625f;                      // /GATE_LOGIT_NORM
    ea = expf(A);
    const size_t orow = ((size_t)bh*2048 + c*64 + t)*128 + dk;
    qt[orow] = f2bf(qv * ea * 0.08838834764831845f);   // DK^-0.5
    kt[orow] = f2bf(kv * expf(-A));
  }
  eac[((size_t)bh*32 + c)*128 + dk] = ea;
}

// ---------------- sequential chunk-state recurrence; stores S at chunk START (bf16) ----------------
__global__ __launch_bounds__(128) void k_seqstate(const unsigned short* __restrict__ kt,
                                                  const unsigned short* __restrict__ proj,
                                                  const float* __restrict__ eac,
                                                  unsigned short* __restrict__ sst)
{
  __shared__ __align__(16) float Ks[64*64];
  __shared__ __align__(16) float Vs[64*32];
  const int bid = blockIdx.x;
  const int bh = bid >> 4, dks = (bid >> 3) & 1, dvs = bid & 7;
  const int b = bh >> 2, h = bh & 3;
  const int tid = threadIdx.x;
  const int dkl = (tid >> 3) * 4, dv0 = (tid & 7) * 4;
  const int vcol0 = 1024 + h*256 + dvs*32;

  f32x4 acc4[4];
  #pragma unroll
  for (int i = 0; i < 4; ++i) { acc4[i][0]=0.f; acc4[i][1]=0.f; acc4[i][2]=0.f; acc4[i][3]=0.f; }

  for (int c = 0; c < 32; ++c) {
    __syncthreads();
    const size_t tok0 = (size_t)b*2048 + c*64;
    #pragma unroll
    for (int it = 0; it < 8; ++it) {        // Ks: 64 x 64 (this block's dk half)
      const int lin = it*512 + tid*4;
      const int t = lin >> 6, dk = lin & 63;
      u16x4 kv = *(const u16x4*)&kt[((size_t)bh*2048 + c*64 + t)*128 + dks*64 + dk];
      *(f32x4*)&Ks[t*64 + dk] = cvt4(kv);
    }
    #pragma unroll
    for (int it = 0; it < 4; ++it) {        // Vs: 64x32
      const int lin = it*512 + tid*4;
      const int t = lin >> 5, j = lin & 31;
      u16x4 vv = *(const u16x4*)&proj[(tok0 + t)*3584 + vcol0 + j];
      *(f32x4*)&Vs[t*32 + j] = cvt4(vv);
    }
    __syncthreads();
    const size_t sbase = (((size_t)bh*32 + c)*128 + dks*64 + dkl)*256 + dvs*32 + dv0;
    #pragma unroll
    for (int i = 0; i < 4; ++i)
      *(u16x4*)&sst[sbase + (size_t)i*256] = pack4(acc4[i]);
    for (int t = 0; t < 64; ++t) {
      const f32x4 ka = *(const f32x4*)&Ks[t*64 + dkl];
      const f32x4 vv = *(const f32x4*)&Vs[t*32 + dv0];
      acc4[0] += vv * ka[0]; acc4[1] += vv * ka[1]; acc4[2] += vv * ka[2]; acc4[3] += vv * ka[3];
    }
    #pragma unroll
    for (int i = 0; i < 4; ++i)
      acc4[i] *= eac[((size_t)bh*32 + c)*128 + dks*64 + dkl + i];
  }
}

// ---------------- P = tril(Qt Kt^T) per (bh, chunk): 64x64 f32 ----------------
__global__ __launch_bounds__(256) void k_ppass(const unsigned short* __restrict__ qt,
                                               const unsigned short* __restrict__ kt,
                                               float* __restrict__ pbuf)
{
  __shared__ __align__(16) float Qs[64*140];
  __shared__ __align__(16) float Ks[64*140];
  const int c = blockIdx.x & 31, bh = blockIdx.x >> 5;
  const int tid = threadIdx.x;
  const int tr = tid >> 4, tc = tid & 15;
  #pragma unroll
  for (int it = 0; it < 8; ++it) {
    const int lin = it*1024 + tid*4;
    const int r = lin >> 7, kk = lin & 127;
    const size_t src = ((size_t)bh*2048 + c*64 + r)*128 + kk;
    *(f32x4*)&Qs[r*140 + kk] = cvt4(*(const u16x4*)&qt[src]);
    *(f32x4*)&Ks[r*140 + kk] = cvt4(*(const u16x4*)&kt[src]);
  }
  __syncthreads();
  float acc_s[4][4];
  #pragma unroll
  for (int r = 0; r < 4; ++r) { acc_s[r][0]=0.f; acc_s[r][1]=0.f; acc_s[r][2]=0.f; acc_s[r][3]=0.f; }
  for (int k0 = 0; k0 < 128; k0 += 4) {
    f32x4 qv[4], kv[4];
    #pragma unroll
    for (int r = 0; r < 4; ++r) qv[r] = *(const f32x4*)&Qs[(tr*4 + r)*140 + k0];
    #pragma unroll
    for (int cc = 0; cc < 4; ++cc) kv[cc] = *(const f32x4*)&Ks[(tc + 16*cc)*140 + k0];
    #pragma unroll
    for (int r = 0; r < 4; ++r) {
      #pragma unroll
      for (int cc = 0; cc < 4; ++cc) {
        #pragma unroll
        for (int i = 0; i < 4; ++i) acc_s[r][cc] += qv[r][i] * kv[cc][i];
      }
    }
  }
  const size_t pb = ((size_t)bh*32 + c)*4096;
  #pragma unroll
  for (int r = 0; r < 4; ++r) {
    const int rg = tr*4 + r;
    #pragma unroll
    for (int cc = 0; cc < 4; ++cc) {
      const int tg = tc + 16*cc;
      pbuf[pb + rg*64 + tg] = (tg <= rg) ? acc_s[r][cc] : 0.f;
    }
  }
}

// ---------------- O = P@V + Qt@S0 per (bh, chunk, dvslice64) -> bf16 ----------------
__global__ __launch_bounds__(256) void k_opass(const float* __restrict__ pbuf,
                                               const unsigned short* __restrict__ proj,
                                               const unsigned short* __restrict__ qt,
                                               const unsigned short* __restrict__ sst,
                                               unsigned short* __restrict__ oraw)
{
  __shared__ __align__(16) float Ps[64*76];
  __shared__ __align__(16) float Vs[64*64];
  __shared__ __align__(16) float Qs[64*132];
  __shared__ __align__(16) float S0s[128*64];
  const int bid = blockIdx.x;
  const int bh = bid >> 7, rem = bid & 127, c = rem >> 2, dvs = rem & 3;
  const int b = bh >> 2, h = bh & 3;
  const int tid = threadIdx.x, tr = tid >> 4, tc = tid & 15;
  const size_t tok0 = (size_t)b*2048 + c*64;
  #pragma unroll
  for (int it = 0; it < 4; ++it) {
    const int lin = it*1024 + tid*4;
    const int r = lin >> 6, t = lin & 63;
    *(f32x4*)&Ps[r*76 + t] = *(const f32x4*)&pbuf[((size_t)bh*32 + c)*4096 + lin];
  }
  #pragma unroll
  for (int it = 0; it < 4; ++it) {
    const int lin = it*1024 + tid*4;
    const int t = lin >> 6, dv = lin & 63;
    *(f32x4*)&Vs[t*64 + dv] = cvt4(*(const u16x4*)&proj[(tok0 + t)*3584 + 1024 + h*256 + dvs*64 + dv]);
  }
  #pragma unroll
  for (int it = 0; it < 8; ++it) {
    const int lin = it*1024 + tid*4;
    const int r = lin >> 7, kk = lin & 127;
    *(f32x4*)&Qs[r*132 + kk] = cvt4(*(const u16x4*)&qt[((size_t)bh*2048 + c*64 + r)*128 + kk]);
  }
  #pragma unroll
  for (int it = 0; it < 8; ++it) {
    const int lin = it*1024 + tid*4;
    const int kk = lin >> 6, dv = lin & 63;
    *(f32x4*)&S0s[kk*64 + dv] = cvt4(*(const u16x4*)&sst[(((size_t)bh*32 + c)*128 + kk)*256 + dvs*64 + dv]);
  }
  __syncthreads();
  f32x4 acc[4];
  #pragma unroll
  for (int r = 0; r < 4; ++r) { acc[r][0]=0.f; acc[r][1]=0.f; acc[r][2]=0.f; acc[r][3]=0.f; }
  for (int t0 = 0; t0 < 64; t0 += 4) {
    f32x4 pv[4];
    #pragma unroll
    for (int r = 0; r < 4; ++r) pv[r] = *(const f32x4*)&Ps[(tr*4 + r)*76 + t0];
    #pragma unroll
    for (int i = 0; i < 4; ++i) {
      const f32x4 vv = *(const f32x4*)&Vs[(t0 + i)*64 + tc*4];
      #pragma unroll
      for (int r = 0; r < 4; ++r) acc[r] += vv * pv[r][i];
    }
  }
  for (int k0 = 0; k0 < 128; k0 += 4) {
    f32x4 qv[4];
    #pragma unroll
    for (int r = 0; r < 4; ++r) qv[r] = *(const f32x4*)&Qs[(tr*4 + r)*132 + k0];
    #pragma unroll
    for (int i = 0; i < 4; ++i) {
      const f32x4 sv = *(const f32x4*)&S0s[(k0 + i)*64 + tc*4];
      #pragma unroll
      for (int r = 0; r < 4; ++r) acc[r] += sv * qv[r][i];
    }
  }
  #pragma unroll
  for (int r = 0; r < 4; ++r)
    *(u16x4*)&oraw[((size_t)bh*2048 + c*64 + tr*4 + r)*256 + dvs*64 + tc*4] = pack4(acc[r]);
}

// ---------------- output gate: rmsnorm(o)*g*sigmoid(g) -> og bf16 token-major [16384][1024] ----------------
__global__ __launch_bounds__(256) void k_gate(const unsigned short* __restrict__ oraw,
                                              const unsigned short* __restrict__ proj,
                                              const float* __restrict__ gnw,
                                              unsigned short* __restrict__ og)
{
  const int token = blockIdx.x;
  const int b = token >> 11, t = token & 2047;
  const int tid = threadIdx.x, h = tid >> 6, lane = tid & 63;
  const int dv = lane * 4;
  const f32x4 of = cvt4(*(const u16x4*)&oraw[(((size_t)(b*4 + h))*2048 + t)*256 + dv]);
  float ss = of[0]*of[0] + of[1]*of[1] + of[2]*of[2] + of[3]*of[3];
  #pragma unroll
  for (int o = 32; o > 0; o >>= 1) ss += __shfl_xor(ss, o);
  const float rs = rsqrtf(ss * (1.f/256.f) + 1e-5f);
  const u16x4 gv = *(const u16x4*)&proj[(size_t)token*3584 + 2048 + h*256 + dv];
  u16x4 res;
  #pragma unroll
  for (int i = 0; i < 4; ++i) {
    const float gf = bf2f(gv[i]);
    const float sw = gf / (1.f + expf(-gf));
    res[i] = f2bf(of[i] * rs * gnw[dv + i] * sw);
  }
  *(u16x4*)&og[(size_t)token*1024 + h*256 + dv] = res;
}

extern "C" void kernel_launch(void* const* d_in, const int* in_sizes, int n_in,
                              void* d_out, int out_size, void* d_ws, size_t ws_size,
                              hipStream_t stream)
{
  (void)in_sizes; (void)n_in; (void)out_size; (void)ws_size;
  const float* x    = (const float*)d_in[0];
  const float* ln1g = (const float*)d_in[1];
  const float* ln1b = (const float*)d_in[2];
  const float* Wq   = (const float*)d_in[3];
  const float* Wk   = (const float*)d_in[4];
  const float* Wv   = (const float*)d_in[5];
  const float* Wg   = (const float*)d_in[6];
  const float* Wgk1 = (const float*)d_in[7];
  const float* Wgk2 = (const float*)d_in[8];
  const float* bgk  = (const float*)d_in[9];
  const float* gnw  = (const float*)d_in[10];
  const float* Wo   = (const float*)d_in[11];
  const float* ln2g = (const float*)d_in[12];
  const float* ln2b = (const float*)d_in[13];
  const float* W1   = (const float*)d_in[14];
  const float* b1   = (const float*)d_in[15];
  const float* W2   = (const float*)d_in[16];
  const float* b2   = (const float*)d_in[17];
  float* out = (float*)d_out;
  char* ws = (char*)d_ws;

  // workspace layout (244,842,496 bytes total); SST lives in d_out (dead before gemm256<1>).
  u16t*  XN   = (u16t*)(ws + 0);
  u16t*  WPT  = (u16t*)(ws + 33554432);
  u16t*  WOT  = (u16t*)(ws + 40894464);
  u16t*  W1T  = (u16t*)(ws + 42991616);
  u16t*  W2T  = (u16t*)(ws + 51380224);
  u16t*  PROJ = (u16t*)(ws + 59768832);
  u16t*  QT   = (u16t*)(ws + 177209344);
  u16t*  KT   = (u16t*)(ws + 193986560);
  float* EAC  = (float*)(ws + 210763776);
  u16t*  ORAW = (u16t*)(ws + 211288064);
  float* PB   = (float*)(ws + 0);           // alias XN (dead after proj GEMM)
  u16t*  OG   = (u16t*)(ws + 0);            // alias XN/PB (PB dead after k_opass)
  u16t*  HID  = PROJ;                       // alias PROJ+QT (dead after k_gate/k_opass)
  u16t*  H2   = ORAW;                       // alias ORAW (dead after k_gate)
  u16t*  SST  = (u16t*)d_out;               // alias d_out (dead before gemm256<1>)

  const dim3 tb(32, 8);
  k_transpose<<<dim3(16,32),  tb, 0, stream>>>(Wq, WPT,                      1024, 512);
  k_transpose<<<dim3(16,32),  tb, 0, stream>>>(Wk, WPT + (size_t)512*1024,   1024, 512);
  k_transpose<<<dim3(32,32),  tb, 0, stream>>>(Wv, WPT + (size_t)1024*1024,  1024, 1024);
  k_transpose<<<dim3(32,32),  tb, 0, stream>>>(Wg, WPT + (size_t)2048*1024,  1024, 1024);
  k_wgk<<<2048, 256, 0, stream>>>(Wgk1, Wgk2, WPT + (size_t)3072*1024);
  k_transpose<<<dim3(32,32),  tb, 0, stream>>>(Wo, WOT, 1024, 1024);
  k_transpose<<<dim3(128,32), tb, 0, stream>>>(W1, W1T, 1024, 4096);
  k_transpose<<<dim3(32,128), tb, 0, stream>>>(W2, W2T, 4096, 1024);

  k_layernorm<<<16384, 256, 0, stream>>>(x, ln1g, ln1b, XN);
  gemm256<0><<<dim3(14,64), 512, 0, stream>>>(XN, WPT, 3584, 1024, nullptr, PROJ, nullptr, nullptr);
  k_scanprep<<<1024, 128, 0, stream>>>(PROJ, bgk, QT, KT, EAC);
  k_seqstate<<<512, 128, 0, stream>>>(KT, PROJ, EAC, SST);
  k_ppass<<<1024, 256, 0, stream>>>(QT, KT, PB);
  k_opass<<<4096, 256, 0, stream>>>(PB, PROJ, QT, SST, ORAW);
  k_gate<<<16384, 256, 0, stream>>>(ORAW, PROJ, gnw, OG);
  gemm256<1><<<dim3(4,64),  512, 0, stream>>>(OG, WOT, 1024, 1024, out, nullptr, x, nullptr);   // x1 = o@Wo + x
  k_layernorm<<<16384, 256, 0, stream>>>(out, ln2g, ln2b, H2);
  gemm256<2><<<dim3(16,64), 512, 0, stream>>>(H2, W1T, 4096, 1024, nullptr, HID, nullptr, b1);  // gelu(h@W1+b1)
  gemm256<3><<<dim3(4,64),  512, 0, stream>>>(HID, W2T, 1024, 4096, out, nullptr, out, b2);     // out = x1 + hid@W2 + b2
}

// Round 6
// 864.185 us; speedup vs baseline: 1.3372x; 1.3372x over previous
//
#include <hip/hip_runtime.h>
#include <stdint.h>

// GLA block for MI355X (gfx950).
// B=8 S=2048 D=1024 H=4 DK=128 DV=256 CHUNK=64 (32 chunks), MLP_H=4096.
// R6: revert GEMM loop to R4 8-phase (best measured). Fix epilogue VALU:
// fast tanh-GELU (native exp2/rcp) replaces erff. Fast log-sigmoid in scanprep.
// k_opass LDS 96->70 KB (bf16 Q/S0 in LDS) -> 2 blocks/CU. Merged transposes.

typedef unsigned short u16t;
typedef __attribute__((ext_vector_type(8))) short bf16x8;
typedef __attribute__((ext_vector_type(4))) float f32x4;
typedef __attribute__((ext_vector_type(4))) unsigned short u16x4;

__device__ __forceinline__ float bf2f(unsigned short u){ union{unsigned int i; float f;} v; v.i=((unsigned int)u)<<16; return v.f; }
__device__ __forceinline__ unsigned short f2bf(float f){ union{unsigned int i; float f;} v; v.f=f; unsigned int r=v.i+0x7FFFu+((v.i>>16)&1u); return (unsigned short)(r>>16); }
__device__ __forceinline__ f32x4 cvt4(u16x4 u){ f32x4 r; r[0]=bf2f(u[0]); r[1]=bf2f(u[1]); r[2]=bf2f(u[2]); r[3]=bf2f(u[3]); return r; }
__device__ __forceinline__ u16x4 pack4(f32x4 f){ u16x4 r; r[0]=f2bf(f[0]); r[1]=f2bf(f[1]); r[2]=f2bf(f[2]); r[3]=f2bf(f[3]); return r; }

// fast tanh-GELU: 0.5t(1+tanh(0.79788456(t+0.044715 t^3))) = t - t/(e+1),
// e = exp2(2.3021183 t + 0.10295465 t^3). |err| vs exact-erf gelu ~3e-4.
__device__ __forceinline__ float gelu_f(float t){
  const float t3 = t*t*t;
  const float y = 2.3021183f*t + 0.10295465f*t3;
  const float e = __builtin_amdgcn_exp2f(y);
  return t - t*__builtin_amdgcn_rcpf(e + 1.f);
}

__device__ __forceinline__ void gload_lds16(const unsigned short* g, unsigned short* l)
{
  __builtin_amdgcn_global_load_lds(
      (const __attribute__((address_space(1))) unsigned int*)g,
      (__attribute__((address_space(3))) unsigned int*)l,
      16, 0, 0);
}

// ---------------- merged transpose f32 [Kin][N] -> bf16 [N][Kin], 7 weights ----------------
__global__ void k_transpose_multi(const float* __restrict__ Wq, const float* __restrict__ Wk,
                                  const float* __restrict__ Wv, const float* __restrict__ Wg,
                                  const float* __restrict__ Wo, const float* __restrict__ W1,
                                  const float* __restrict__ W2,
                                  unsigned short* __restrict__ WPT, unsigned short* __restrict__ WOT,
                                  unsigned short* __restrict__ W1T, unsigned short* __restrict__ W2T)
{
  __shared__ float tile[32][33];
  int bid = blockIdx.x;
  const float* src; unsigned short* dst; int Kin, N, nx;
  if      (bid < 512)  { src=Wq; dst=WPT;                          Kin=1024; N=512;  nx=16;  }
  else if (bid < 1024) { src=Wk; dst=WPT+(size_t)512*1024;         Kin=1024; N=512;  nx=16;  bid-=512;  }
  else if (bid < 2048) { src=Wv; dst=WPT+(size_t)1024*1024;        Kin=1024; N=1024; nx=32;  bid-=1024; }
  else if (bid < 3072) { src=Wg; dst=WPT+(size_t)2048*1024;        Kin=1024; N=1024; nx=32;  bid-=2048; }
  else if (bid < 4096) { src=Wo; dst=WOT;                          Kin=1024; N=1024; nx=32;  bid-=3072; }
  else if (bid < 8192) { src=W1; dst=W1T;                          Kin=1024; N=4096; nx=128; bid-=4096; }
  else                 { src=W2; dst=W2T;                          Kin=4096; N=1024; nx=32;  bid-=8192; }
  const int n0 = (bid % nx)*32, k0 = (bid / nx)*32;
  const int tx = threadIdx.x, ty = threadIdx.y;
  #pragma unroll
  for (int i = 0; i < 4; ++i)
    tile[ty + i*8][tx] = src[(size_t)(k0 + ty + i*8)*N + n0 + tx];
  __syncthreads();
  #pragma unroll
  for (int i = 0; i < 4; ++i)
    dst[(size_t)(n0 + ty + i*8)*Kin + k0 + tx] = f2bf(tile[tx][ty + i*8]);
}

// ---------------- Wgk = Wgk1[1024,16] @ Wgk2[16,512] -> bf16 transposed rows [512][1024] ----------------
__global__ void k_wgk(const float* __restrict__ Wgk1, const float* __restrict__ Wgk2, unsigned short* __restrict__ dstT)
{
  const int idx = blockIdx.x*256 + threadIdx.x;   // 1024*512 total
  const int i = idx & 1023, j = idx >> 10;
  float s = 0.f;
  #pragma unroll
  for (int r = 0; r < 16; ++r) s += Wgk1[i*16 + r] * Wgk2[r*512 + j];
  dstT[(size_t)j*1024 + i] = f2bf(s);
}

// ---------------- LayerNorm row=1024, f32 in -> bf16 out ----------------
__global__ __launch_bounds__(256) void k_layernorm(const float* __restrict__ x, const float* __restrict__ g,
                                                   const float* __restrict__ b, unsigned short* __restrict__ out)
{
  const int row = blockIdx.x, tid = threadIdx.x;
  const float4 xv = *(const float4*)&x[(size_t)row*1024 + tid*4];
  float s  = xv.x + xv.y + xv.z + xv.w;
  float sq = xv.x*xv.x + xv.y*xv.y + xv.z*xv.z + xv.w*xv.w;
  #pragma unroll
  for (int o = 32; o > 0; o >>= 1) { s += __shfl_xor(s, o); sq += __shfl_xor(sq, o); }
  __shared__ float red[8];
  const int w = tid >> 6;
  if ((tid & 63) == 0) { red[w] = s; red[4 + w] = sq; }
  __syncthreads();
  s  = red[0] + red[1] + red[2] + red[3];
  sq = red[4] + red[5] + red[6] + red[7];
  const float mu = s * (1.f/1024.f);
  const float var = sq * (1.f/1024.f) - mu*mu;
  const float rs = rsqrtf(var + 1e-5f);
  float xe[4] = {xv.x, xv.y, xv.z, xv.w};
  u16x4 o4;
  #pragma unroll
  for (int i = 0; i < 4; ++i) {
    const int c = tid*4 + i;
    o4[i] = f2bf((xe[i] - mu) * rs * g[c] + b[c]);
  }
  *(u16x4*)&out[(size_t)row*1024 + tid*4] = o4;
}

// ---------------- 256x256 8-phase bf16 MFMA GEMM: C = A[M,K] @ Bt[N,K]^T ----------------
// 512 threads = 8 waves (2M x 4N); per-wave 128x64 output (8x4 frags of 16x16).
// LDS: 2 bufs x 4 chunks {Ah0,Ah1,Bh0,Bh1} x 16KB = 128 KiB. XOR-swizzled (T2).
// EPI: 0 = store bf16; 1 = +resid -> f32; 2 = +bias, gelu -> bf16; 3 = +bias +resid -> f32
template<int EPI>
__global__ __launch_bounds__(512, 2)
void gemm256(const unsigned short* __restrict__ A, const unsigned short* __restrict__ Bt,
             int N, int K,
             float* outF, unsigned short* outH,
             const float* resid, const float* bias)
{
  __shared__ __align__(16) unsigned short lds[65536];   // 128 KiB
  const int tid = threadIdx.x;
  const int lane = tid & 63, w = tid >> 6;
  const int wr = w >> 2, wc = w & 3;
  const int l15 = lane & 15, lq = lane >> 4;

  // bijective XCD-aware swizzle (m204)
  const int nwg = gridDim.x * gridDim.y;
  const int bid = blockIdx.y * gridDim.x + blockIdx.x;
  const int q = nwg >> 3, r = nwg & 7;
  const int xcd = bid & 7, lid = bid >> 3;
  const int sw = (xcd < r ? xcd*(q+1) : r*(q+1) + (xcd - r)*q) + lid;
  const int row0 = (sw / gridDim.x) * 256;
  const int col0 = (sw % gridDim.x) * 256;

  // staging personal constants: 2 loads per chunk; load L covers rows L*64..L*64+63
  const int rA_ = tid >> 3;                              // row within 64-row half
  const int cswz = 8 * ((tid & 7) ^ (rA_ & 7));          // pre-swizzled source col (elems)
  const unsigned short* baseA[2][2];
  const unsigned short* baseB[2][2];
  #pragma unroll
  for (int h = 0; h < 2; ++h)
    #pragma unroll
    for (int L = 0; L < 2; ++L) {
      baseA[h][L] = A  + (size_t)(row0 + h*128 + L*64 + rA_) * K + cswz;
      baseB[h][L] = Bt + (size_t)(col0 + h*128 + L*64 + rA_) * K + cswz;
    }

  const int NT = K >> 6;          // 64-wide K tiles (even count: K%128==0)
  const int NI = NT >> 1;

  f32x4 acc[8][4];
  #pragma unroll
  for (int m = 0; m < 8; ++m)
    #pragma unroll
    for (int n = 0; n < 4; ++n) { acc[m][n][0]=0.f; acc[m][n][1]=0.f; acc[m][n][2]=0.f; acc[m][n][3]=0.f; }

  bf16x8 af[4][2];          // A frags for current qm (mm, khalf)
  bf16x8 bfr[2][2][2];      // B frags (qn, nn, khalf)

  // chunk ids: 0=Ah0, 1=Ah1, 2=Bh0, 3=Bh1
  #define STAGE(CH, T)                                                         \
    {                                                                          \
      const int tt = ((T) < NT) ? (T) : (T) - 2;  /* tail: restage same data */\
      const int dbase = (tt & 1) * 32768 + (CH) * 8192;                        \
      const int ktt = tt << 6;                                                 \
      _Pragma("unroll")                                                        \
      for (int L = 0; L < 2; ++L) {                                            \
        const unsigned short* gp =                                             \
            ((CH) < 2 ? baseA[(CH) & 1][L] : baseB[(CH) & 1][L]) + ktt;        \
        gload_lds16(gp, (unsigned short*)&lds[dbase + L*4096 + w*512]);        \
      }                                                                        \
    }

  #define DS_A(CB)                                                             \
    { _Pragma("unroll")                                                        \
      for (int mm = 0; mm < 4; ++mm) {                                         \
        const int rl = wr*64 + mm*16 + l15;                                    \
        const int co = (l15 & 7) * 8;                                          \
        af[mm][0] = *(const bf16x8*)&lds[(CB) + rl*64 + ((lq*8) ^ co)];        \
        af[mm][1] = *(const bf16x8*)&lds[(CB) + rl*64 + ((32 + lq*8) ^ co)];   \
      } }

  #define DS_B(CB, QN)                                                         \
    { _Pragma("unroll")                                                        \
      for (int nn = 0; nn < 2; ++nn) {                                         \
        const int rl = wc*32 + nn*16 + l15;                                    \
        const int co = (l15 & 7) * 8;                                          \
        bfr[QN][nn][0] = *(const bf16x8*)&lds[(CB) + (2+(QN))*8192 + rl*64 + ((lq*8) ^ co)];      \
        bfr[QN][nn][1] = *(const bf16x8*)&lds[(CB) + (2+(QN))*8192 + rl*64 + ((32 + lq*8) ^ co)]; \
      } }

  #define PRE_MFMA()                                                           \
    { __builtin_amdgcn_s_barrier();                                            \
      asm volatile("s_waitcnt lgkmcnt(0)" ::: "memory");                       \
      __builtin_amdgcn_sched_barrier(0); }

  #define MMA(QM, QN)                                                          \
    { __builtin_amdgcn_s_setprio(1);                                           \
      _Pragma("unroll")                                                        \
      for (int mm = 0; mm < 4; ++mm)                                           \
        _Pragma("unroll")                                                      \
        for (int nn = 0; nn < 2; ++nn) {                                       \
          acc[(QM)*4+mm][(QN)*2+nn] = __builtin_amdgcn_mfma_f32_16x16x32_bf16( \
              af[mm][0], bfr[QN][nn][0], acc[(QM)*4+mm][(QN)*2+nn], 0, 0, 0);  \
          acc[(QM)*4+mm][(QN)*2+nn] = __builtin_amdgcn_mfma_f32_16x16x32_bf16( \
              af[mm][1], bfr[QN][nn][1], acc[(QM)*4+mm][(QN)*2+nn], 0, 0, 0);  \
        }                                                                      \
      __builtin_amdgcn_s_setprio(0); }

  #define POSTW(VN)                                                            \
    { asm volatile("s_waitcnt vmcnt(" #VN ")" ::: "memory");                   \
      __builtin_amdgcn_sched_barrier(0);                                       \
      __builtin_amdgcn_s_barrier(); }

  #define POSTN() { __builtin_amdgcn_s_barrier(); }

  // prologue: mimic steady-state issue stream c3..c8 for tiles 0,1
  STAGE(0, 0); STAGE(2, 0); STAGE(1, 0); STAGE(3, 0); STAGE(0, 1); STAGE(2, 1);
  asm volatile("s_waitcnt vmcnt(8)" ::: "memory");   // Ah0(0), Bh0(0) landed
  __builtin_amdgcn_sched_barrier(0);
  __builtin_amdgcn_s_barrier();

  for (int i = 0; i < NI; ++i) {
    const int t0 = 2*i, t1 = 2*i + 1;
    // P1: quad (0,0) of t0
    DS_A(0); DS_B(0, 0); STAGE(1, t1);
    PRE_MFMA(); MMA(0, 0); POSTW(6);
    // P2: quad (0,1)
    DS_B(0, 1); STAGE(3, t1);
    PRE_MFMA(); MMA(0, 1); POSTN();
    // P3: quad (1,0)
    DS_A(8192); STAGE(0, t0 + 2);
    PRE_MFMA(); MMA(1, 0); POSTN();
    // P4: quad (1,1)
    STAGE(2, t0 + 2);
    PRE_MFMA(); MMA(1, 1); POSTW(8);
    // P5: quad (0,0) of t1
    DS_A(32768); DS_B(32768, 0); STAGE(1, t0 + 2);
    PRE_MFMA(); MMA(0, 0); POSTW(6);
    // P6: quad (0,1)
    DS_B(32768, 1); STAGE(3, t0 + 2);
    PRE_MFMA(); MMA(0, 1); POSTN();
    // P7: quad (1,0)
    DS_A(32768 + 8192); STAGE(0, t1 + 2);
    PRE_MFMA(); MMA(1, 0); POSTN();
    // P8: quad (1,1)
    STAGE(2, t1 + 2);
    PRE_MFMA(); MMA(1, 1); POSTW(8);
  }
  #undef STAGE
  #undef DS_A
  #undef DS_B
  #undef PRE_MFMA
  #undef MMA
  #undef POSTW
  #undef POSTN

  // epilogue
  #pragma unroll
  for (int qm = 0; qm < 2; ++qm)
    #pragma unroll
    for (int mm = 0; mm < 4; ++mm)
      #pragma unroll
      for (int qn = 0; qn < 2; ++qn)
        #pragma unroll
        for (int nn = 0; nn < 2; ++nn)
          #pragma unroll
          for (int ii = 0; ii < 4; ++ii) {
            const int rr = row0 + qm*128 + wr*64 + mm*16 + lq*4 + ii;
            const int cc = col0 + qn*128 + wc*32 + nn*16 + l15;
            const size_t idx = (size_t)rr * N + cc;
            const float v = acc[qm*4+mm][qn*2+nn][ii];
            if constexpr (EPI == 0) {
              outH[idx] = f2bf(v);
            } else if constexpr (EPI == 1) {
              outF[idx] = v + resid[idx];
            } else if constexpr (EPI == 2) {
              outH[idx] = f2bf(gelu_f(v + bias[cc]));
            } else {
              outF[idx] = v + bias[cc] + resid[idx];
            }
          }
}

// ---------------- scan prep: per (bh, chunk): cumsum gates, write qt/kt bf16, eac f32 ----------------
__global__ __launch_bounds__(128) void k_scanprep(const unsigned short* __restrict__ proj, const float* __restrict__ bgk,
                                                  unsigned short* __restrict__ qt, unsigned short* __restrict__ kt,
                                                  float* __restrict__ eac)
{
  const int c = blockIdx.x & 31, bh = blockIdx.x >> 5;
  const int b = bh >> 2, h = bh & 3;
  const int dk = threadIdx.x;
  const size_t tok0 = (size_t)b*2048 + c*64;
  const float bg = bgk[h*128 + dk];
  float A = 0.f, ea = 1.f;
  for (int t = 0; t < 64; ++t) {
    const size_t prow = (tok0 + t) * 3584;
    const float qv = bf2f(proj[prow + h*128 + dk]);
    const float kv = bf2f(proj[prow + 512 + h*128 + dk]);
    const float z = bf2f(proj[prow + 3072 + h*128 + dk]) + bg;
    // log_sigmoid(z) = min(z,0) - ln2*log2(1+exp2(-|z|*log2e)); native exp2/log2
    const float az = fabsf(z);
    const float sp = fmaxf(-z, 0.f)
                   + 0.69314718f*__builtin_amdgcn_logf(1.f + __builtin_amdgcn_exp2f(-1.44269504f*az));
    A -= sp * 0.0625f;                      // += log_sigmoid(z)/GATE_LOGIT_NORM
    ea = __builtin_amdgcn_exp2f(A * 1.44269504f);          // e^A (A<=0, ea<=1)
    const float em = __builtin_amdgcn_rcpf(ea);            // e^-A
    const size_t orow = ((size_t)bh*2048 + c*64 + t)*128 + dk;
    qt[orow] = f2bf(qv * ea * 0.08838834764831845f);   // DK^-0.5
    kt[orow] = f2bf(kv * em);
  }
  eac[((size_t)bh*32 + c)*128 + dk] = ea;
}

// ---------------- sequential chunk-state recurrence; stores S at chunk START (bf16) ----------------
__global__ __launch_bounds__(128) void k_seqstate(const unsigned short* __restrict__ kt,
                                                  const unsigned short* __restrict__ proj,
                                                  const float* __restrict__ eac,
                                                  unsigned short* __restrict__ sst)
{
  __shared__ __align__(16) float Ks[64*64];
  __shared__ __align__(16) float Vs[64*32];
  const int bid = blockIdx.x;
  const int bh = bid >> 4, dks = (bid >> 3) & 1, dvs = bid & 7;
  const int b = bh >> 2, h = bh & 3;
  const int tid = threadIdx.x;
  const int dkl = (tid >> 3) * 4, dv0 = (tid & 7) * 4;
  const int vcol0 = 1024 + h*256 + dvs*32;

  f32x4 acc4[4];
  #pragma unroll
  for (int i = 0; i < 4; ++i) { acc4[i][0]=0.f; acc4[i][1]=0.f; acc4[i][2]=0.f; acc4[i][3]=0.f; }

  for (int c = 0; c < 32; ++c) {
    __syncthreads();
    const size_t tok0 = (size_t)b*2048 + c*64;
    #pragma unroll
    for (int it = 0; it < 8; ++it) {        // Ks: 64 x 64 (this block's dk half)
      const int lin = it*512 + tid*4;
      const int t = lin >> 6, dk = lin & 63;
      u16x4 kv = *(const u16x4*)&kt[((size_t)bh*2048 + c*64 + t)*128 + dks*64 + dk];
      *(f32x4*)&Ks[t*64 + dk] = cvt4(kv);
    }
    #pragma unroll
    for (int it = 0; it < 4; ++it) {        // Vs: 64x32
      const int lin = it*512 + tid*4;
      const int t = lin >> 5, j = lin & 31;
      u16x4 vv = *(const u16x4*)&proj[(tok0 + t)*3584 + vcol0 + j];
      *(f32x4*)&Vs[t*32 + j] = cvt4(vv);
    }
    __syncthreads();
    const size_t sbase = (((size_t)bh*32 + c)*128 + dks*64 + dkl)*256 + dvs*32 + dv0;
    #pragma unroll
    for (int i = 0; i < 4; ++i)
      *(u16x4*)&sst[sbase + (size_t)i*256] = pack4(acc4[i]);
    for (int t = 0; t < 64; ++t) {
      const f32x4 ka = *(const f32x4*)&Ks[t*64 + dkl];
      const f32x4 vv = *(const f32x4*)&Vs[t*32 + dv0];
      acc4[0] += vv * ka[0]; acc4[1] += vv * ka[1]; acc4[2] += vv * ka[2]; acc4[3] += vv * ka[3];
    }
    #pragma unroll
    for (int i = 0; i < 4; ++i)
      acc4[i] *= eac[((size_t)bh*32 + c)*128 + dks*64 + dkl + i];
  }
}

// ---------------- P = tril(Qt Kt^T) per (bh, chunk): 64x64 f32 ----------------
__global__ __launch_bounds__(256) void k_ppass(const unsigned short* __restrict__ qt,
                                               const unsigned short* __restrict__ kt,
                                               float* __restrict__ pbuf)
{
  __shared__ __align__(16) float Qs[64*140];
  __shared__ __align__(16) float Ks[64*140];
  const int c = blockIdx.x & 31, bh = blockIdx.x >> 5;
  const int tid = threadIdx.x;
  const int tr = tid >> 4, tc = tid & 15;
  #pragma unroll
  for (int it = 0; it < 8; ++it) {
    const int lin = it*1024 + tid*4;
    const int r = lin >> 7, kk = lin & 127;
    const size_t src = ((size_t)bh*2048 + c*64 + r)*128 + kk;
    *(f32x4*)&Qs[r*140 + kk] = cvt4(*(const u16x4*)&qt[src]);
    *(f32x4*)&Ks[r*140 + kk] = cvt4(*(const u16x4*)&kt[src]);
  }
  __syncthreads();
  float acc_s[4][4];
  #pragma unroll
  for (int r = 0; r < 4; ++r) { acc_s[r][0]=0.f; acc_s[r][1]=0.f; acc_s[r][2]=0.f; acc_s[r][3]=0.f; }
  for (int k0 = 0; k0 < 128; k0 += 4) {
    f32x4 qv[4], kv[4];
    #pragma unroll
    for (int r = 0; r < 4; ++r) qv[r] = *(const f32x4*)&Qs[(tr*4 + r)*140 + k0];
    #pragma unroll
    for (int cc = 0; cc < 4; ++cc) kv[cc] = *(const f32x4*)&Ks[(tc + 16*cc)*140 + k0];
    #pragma unroll
    for (int r = 0; r < 4; ++r) {
      #pragma unroll
      for (int cc = 0; cc < 4; ++cc) {
        #pragma unroll
        for (int i = 0; i < 4; ++i) acc_s[r][cc] += qv[r][i] * kv[cc][i];
      }
    }
  }
  const size_t pb = ((size_t)bh*32 + c)*4096;
  #pragma unroll
  for (int r = 0; r < 4; ++r) {
    const int rg = tr*4 + r;
    #pragma unroll
    for (int cc = 0; cc < 4; ++cc) {
      const int tg = tc + 16*cc;
      pbuf[pb + rg*64 + tg] = (tg <= rg) ? acc_s[r][cc] : 0.f;
    }
  }
}

// ---------------- O = P@V + Qt@S0 per (bh, chunk, dvslice64) -> bf16 ----------------
// LDS ~70 KB (Q,S0 kept bf16) -> 2 blocks/CU.
__global__ __launch_bounds__(256) void k_opass(const float* __restrict__ pbuf,
                                               const unsigned short* __restrict__ proj,
                                               const unsigned short* __restrict__ qt,
                                               const unsigned short* __restrict__ sst,
                                               unsigned short* __restrict__ oraw)
{
  __shared__ __align__(16) float Ps[64*76];
  __shared__ __align__(16) float Vs[64*64];
  __shared__ __align__(16) unsigned short Qh[64*136];
  __shared__ __align__(16) unsigned short Sh[128*64];
  const int bid = blockIdx.x;
  const int bh = bid >> 7, rem = bid & 127, c = rem >> 2, dvs = rem & 3;
  const int b = bh >> 2, h = bh & 3;
  const int tid = threadIdx.x, tr = tid >> 4, tc = tid & 15;
  const size_t tok0 = (size_t)b*2048 + c*64;
  #pragma unroll
  for (int it = 0; it < 4; ++it) {
    const int lin = it*1024 + tid*4;
    const int r = lin >> 6, t = lin & 63;
    *(f32x4*)&Ps[r*76 + t] = *(const f32x4*)&pbuf[((size_t)bh*32 + c)*4096 + lin];
  }
  #pragma unroll
  for (int it = 0; it < 4; ++it) {
    const int lin = it*1024 + tid*4;
    const int t = lin >> 6, dv = lin & 63;
    *(f32x4*)&Vs[t*64 + dv] = cvt4(*(const u16x4*)&proj[(tok0 + t)*3584 + 1024 + h*256 + dvs*64 + dv]);
  }
  #pragma unroll
  for (int it = 0; it < 8; ++it) {
    const int lin = it*1024 + tid*4;
    const int rr = lin >> 7, kk = lin & 127;
    *(u16x4*)&Qh[rr*136 + kk] = *(const u16x4*)&qt[((size_t)bh*2048 + c*64 + rr)*128 + kk];
  }
  #pragma unroll
  for (int it = 0; it < 8; ++it) {
    const int lin = it*1024 + tid*4;
    const int kk = lin >> 6, dv = lin & 63;
    *(u16x4*)&Sh[lin] = *(const u16x4*)&sst[(((size_t)bh*32 + c)*128 + kk)*256 + dvs*64 + dv];
  }
  __syncthreads();
  f32x4 acc[4];
  #pragma unroll
  for (int r = 0; r < 4; ++r) { acc[r][0]=0.f; acc[r][1]=0.f; acc[r][2]=0.f; acc[r][3]=0.f; }
  for (int t0 = 0; t0 < 64; t0 += 4) {
    f32x4 pv[4];
    #pragma unroll
    for (int r = 0; r < 4; ++r) pv[r] = *(const f32x4*)&Ps[(tr*4 + r)*76 + t0];
    #pragma unroll
    for (int i = 0; i < 4; ++i) {
      const f32x4 vv = *(const f32x4*)&Vs[(t0 + i)*64 + tc*4];
      #pragma unroll
      for (int r = 0; r < 4; ++r) acc[r] += vv * pv[r][i];
    }
  }
  for (int k0 = 0; k0 < 128; k0 += 4) {
    f32x4 qv[4];
    #pragma unroll
    for (int r = 0; r < 4; ++r) qv[r] = cvt4(*(const u16x4*)&Qh[(tr*4 + r)*136 + k0]);
    #pragma unroll
    for (int i = 0; i < 4; ++i) {
      const f32x4 sv = cvt4(*(const u16x4*)&Sh[(k0 + i)*64 + tc*4]);
      #pragma unroll
      for (int r = 0; r < 4; ++r) acc[r] += sv * qv[r][i];
    }
  }
  #pragma unroll
  for (int r = 0; r < 4; ++r)
    *(u16x4*)&oraw[((size_t)bh*2048 + c*64 + tr*4 + r)*256 + dvs*64 + tc*4] = pack4(acc[r]);
}

// ---------------- output gate: rmsnorm(o)*g*sigmoid(g) -> og bf16 token-major [16384][1024] ----------------
__global__ __launch_bounds__(256) void k_gate(const unsigned short* __restrict__ oraw,
                                              const unsigned short* __restrict__ proj,
                                              const float* __restrict__ gnw,
                                              unsigned short* __restrict__ og)
{
  const int token = blockIdx.x;
  const int b = token >> 11, t = token & 2047;
  const int tid = threadIdx.x, h = tid >> 6, lane = tid & 63;
  const int dv = lane * 4;
  const f32x4 of = cvt4(*(const u16x4*)&oraw[(((size_t)(b*4 + h))*2048 + t)*256 + dv]);
  float ss = of[0]*of[0] + of[1]*of[1] + of[2]*of[2] + of[3]*of[3];
  #pragma unroll
  for (int o = 32; o > 0; o >>= 1) ss += __shfl_xor(ss, o);
  const float rs = rsqrtf(ss * (1.f/256.f) + 1e-5f);
  const u16x4 gv = *(const u16x4*)&proj[(size_t)token*3584 + 2048 + h*256 + dv];
  u16x4 res;
  #pragma unroll
  for (int i = 0; i < 4; ++i) {
    const float gf = bf2f(gv[i]);
    const float sw = gf * __builtin_amdgcn_rcpf(1.f + __builtin_amdgcn_exp2f(-1.44269504f*gf));
    res[i] = f2bf(of[i] * rs * gnw[dv + i] * sw);
  }
  *(u16x4*)&og[(size_t)token*1024 + h*256 + dv] = res;
}

extern "C" void kernel_launch(void* const* d_in, const int* in_sizes, int n_in,
                              void* d_out, int out_size, void* d_ws, size_t ws_size,
                              hipStream_t stream)
{
  (void)in_sizes; (void)n_in; (void)out_size; (void)ws_size;
  const float* x    = (const float*)d_in[0];
  const float* ln1g = (const float*)d_in[1];
  const float* ln1b = (const float*)d_in[2];
  const float* Wq   = (const float*)d_in[3];
  const float* Wk   = (const float*)d_in[4];
  const float* Wv   = (const float*)d_in[5];
  const float* Wg   = (const float*)d_in[6];
  const float* Wgk1 = (const float*)d_in[7];
  const float* Wgk2 = (const float*)d_in[8];
  const float* bgk  = (const float*)d_in[9];
  const float* gnw  = (const float*)d_in[10];
  const float* Wo   = (const float*)d_in[11];
  const float* ln2g = (const float*)d_in[12];
  const float* ln2b = (const float*)d_in[13];
  const float* W1   = (const float*)d_in[14];
  const float* b1   = (const float*)d_in[15];
  const float* W2   = (const float*)d_in[16];
  const float* b2   = (const float*)d_in[17];
  float* out = (float*)d_out;
  char* ws = (char*)d_ws;

  // workspace layout (244,842,496 bytes total); SST lives in d_out (dead before gemm256<1>).
  u16t*  XN   = (u16t*)(ws + 0);
  u16t*  WPT  = (u16t*)(ws + 33554432);
  u16t*  WOT  = (u16t*)(ws + 40894464);
  u16t*  W1T  = (u16t*)(ws + 42991616);
  u16t*  W2T  = (u16t*)(ws + 51380224);
  u16t*  PROJ = (u16t*)(ws + 59768832);
  u16t*  QT   = (u16t*)(ws + 177209344);
  u16t*  KT   = (u16t*)(ws + 193986560);
  float* EAC  = (float*)(ws + 210763776);
  u16t*  ORAW = (u16t*)(ws + 211288064);
  float* PB   = (float*)(ws + 0);           // alias XN (dead after proj GEMM)
  u16t*  OG   = (u16t*)(ws + 0);            // alias XN/PB (PB dead after k_opass)
  u16t*  HID  = PROJ;                       // alias PROJ+QT (dead after k_gate/k_opass)
  u16t*  H2   = ORAW;                       // alias ORAW (dead after k_gate)
  u16t*  SST  = (u16t*)d_out;               // alias d_out (dead before gemm256<1>)

  k_transpose_multi<<<12288, dim3(32,8), 0, stream>>>(Wq, Wk, Wv, Wg, Wo, W1, W2, WPT, WOT, W1T, W2T);
  k_wgk<<<2048, 256, 0, stream>>>(Wgk1, Wgk2, WPT + (size_t)3072*1024);

  k_layernorm<<<16384, 256, 0, stream>>>(x, ln1g, ln1b, XN);
  gemm256<0><<<dim3(14,64), 512, 0, stream>>>(XN, WPT, 3584, 1024, nullptr, PROJ, nullptr, nullptr);
  k_scanprep<<<1024, 128, 0, stream>>>(PROJ, bgk, QT, KT, EAC);
  k_seqstate<<<512, 128, 0, stream>>>(KT, PROJ, EAC, SST);
  k_ppass<<<1024, 256, 0, stream>>>(QT, KT, PB);
  k_opass<<<4096, 256, 0, stream>>>(PB, PROJ, QT, SST, ORAW);
  k_gate<<<16384, 256, 0, stream>>>(ORAW, PROJ, gnw, OG);
  gemm256<1><<<dim3(4,64),  512, 0, stream>>>(OG, WOT, 1024, 1024, out, nullptr, x, nullptr);   // x1 = o@Wo + x
  k_layernorm<<<16384, 256, 0, stream>>>(out, ln2g, ln2b, H2);
  gemm256<2><<<dim3(16,64), 512, 0, stream>>>(H2, W1T, 4096, 1024, nullptr, HID, nullptr, b1);  // gelu(h@W1+b1)
  gemm256<3><<<dim3(4,64),  512, 0, stream>>>(HID, W2T, 1024, 4096, out, nullptr, out, b2);     // out = x1 + hid@W2 + b2
}